// Round 1
// baseline (3207.966 us; speedup 1.0000x reference)
//
#include <hip/hip_runtime.h>

// LPKT forward. B=64, S=128, NQ=2000, C=128, K=64, DE=DC=64.
// Strategy: precompute all carry-independent terms; main kernel = 1 WG per
// batch element, h[128][64] resident in LDS across the 127 sequential steps.

constexpr int BB = 64;    // batch
constexpr int SS = 128;   // seq len
constexpr int CD = 128;   // C (concepts)
constexpr int KK = 64;    // K
constexpr int HP = 68;    // padded row stride for h in LDS (bank decorrelation, 16B aligned)

// ---------------------------------------------------------------------------
// P1: all_learning = [e_emb|c_emb]@W1+b1, then project through W2/W3 slabs:
//   A2[b,s] = al@W2[0:64]   (learning_pre slot)   B2[b,s] = al@W2[64:128] (learning slot)
//   A3,B3 same with W3.
__global__ void precompute1(const int* __restrict__ qs, const int* __restrict__ cs,
                            const float* __restrict__ Eq, const float* __restrict__ Ec,
                            const float* __restrict__ W1, const float* __restrict__ b1,
                            const float* __restrict__ W2, const float* __restrict__ W3,
                            float* __restrict__ A2, float* __restrict__ B2,
                            float* __restrict__ A3, float* __restrict__ B3) {
  int bs = blockIdx.x;
  int k  = threadIdx.x;            // 0..63
  int q  = qs[bs], cr = cs[bs];
  __shared__ float eq[64], ec[64], al[64];
  eq[k] = Eq[q * 64 + k];
  ec[k] = Ec[cr * 64 + k];
  __syncthreads();
  float a0 = 0.f, a1 = 0.f, a2i = 0.f, a3i = 0.f;
  #pragma unroll
  for (int d = 0; d < 64; d += 4) {
    a0  += eq[d]   * W1[d * 64 + k];
    a1  += eq[d+1] * W1[(d+1) * 64 + k];
    a2i += eq[d+2] * W1[(d+2) * 64 + k];
    a3i += eq[d+3] * W1[(d+3) * 64 + k];
  }
  #pragma unroll
  for (int d = 0; d < 64; d += 4) {
    a0  += ec[d]   * W1[(64+d) * 64 + k];
    a1  += ec[d+1] * W1[(64+d+1) * 64 + k];
    a2i += ec[d+2] * W1[(64+d+2) * 64 + k];
    a3i += ec[d+3] * W1[(64+d+3) * 64 + k];
  }
  al[k] = ((a0 + a1) + (a2i + a3i)) + b1[k];
  __syncthreads();
  float r2a = 0.f, r2b = 0.f, r3a = 0.f, r3b = 0.f;
  float s2a = 0.f, s2b = 0.f, s3a = 0.f, s3b = 0.f;
  #pragma unroll
  for (int j = 0; j < 64; j += 2) {
    float v0 = al[j], v1 = al[j+1];
    r2a += v0 * W2[j * 64 + k];        s2a += v1 * W2[(j+1) * 64 + k];
    r2b += v0 * W2[(64+j) * 64 + k];   s2b += v1 * W2[(64+j+1) * 64 + k];
    r3a += v0 * W3[j * 64 + k];        s3a += v1 * W3[(j+1) * 64 + k];
    r3b += v0 * W3[(64+j) * 64 + k];   s3b += v1 * W3[(64+j+1) * 64 + k];
  }
  A2[bs * 64 + k] = r2a + s2a;
  B2[bs * 64 + k] = r2b + s2b;
  A3[bs * 64 + k] = r3a + s3a;
  B3[bs * 64 + k] = r3b + s3b;
}

// ---------------------------------------------------------------------------
// P2: DIFFQ[b,s,c] = sigmoid(E_q[q]@Wdiff[:,c]+bdiff[c]) * q_matrix[q,c]
//     DISC[b,s]    = sigmoid(E_q[q]@Wdisc+bdisc)*5
__global__ void precompute2(const int* __restrict__ qs, const float* __restrict__ Eq,
                            const float* __restrict__ qmat,
                            const float* __restrict__ Wdiff, const float* __restrict__ bdiff,
                            const float* __restrict__ Wdisc, const float* __restrict__ bdisc,
                            float* __restrict__ DIFFQ, float* __restrict__ DISC) {
  int bs = blockIdx.x;
  int c  = threadIdx.x;            // 0..127
  int q  = qs[bs];
  __shared__ float e[64];
  if (c < 64) e[c] = Eq[q * 64 + c];
  __syncthreads();
  float a0 = 0.f, a1 = 0.f, a2 = 0.f, a3 = 0.f;
  #pragma unroll
  for (int d = 0; d < 64; d += 4) {
    a0 += e[d]   * Wdiff[d * 128 + c];
    a1 += e[d+1] * Wdiff[(d+1) * 128 + c];
    a2 += e[d+2] * Wdiff[(d+2) * 128 + c];
    a3 += e[d+3] * Wdiff[(d+3) * 128 + c];
  }
  float acc = ((a0 + a1) + (a2 + a3)) + bdiff[c];
  float qv  = qmat[q * 128 + c];
  DIFFQ[bs * 128 + c] = qv / (1.f + __expf(-acc));
  if (c == 0) {
    float d0 = 0.f, d1 = 0.f;
    #pragma unroll
    for (int d = 0; d < 64; d += 2) { d0 += e[d] * Wdisc[d]; d1 += e[d+1] * Wdisc[d+1]; }
    float a = d0 + d1 + bdisc[0];
    DISC[bs] = 5.f / (1.f + __expf(-a));
  }
}

// ---------------------------------------------------------------------------
// Main sequential kernel: grid=64 (one WG per batch), block=512 (8 waves).
// Thread tile: 4c x 4k; kb = tid&15 (k quad), cb = tid>>4 (c quad).
// Wave w owns h rows 16w..16w+15 -> no cross-wave hazard on h.
__global__ __launch_bounds__(512) void lpkt_main(
    const int* __restrict__ qs, const float* __restrict__ qmat,
    const float* __restrict__ h0,
    const float* __restrict__ W2, const float* __restrict__ b2,
    const float* __restrict__ W3, const float* __restrict__ b3,
    const float* __restrict__ W4, const float* __restrict__ b4,
    const float* __restrict__ Wab, const float* __restrict__ bab,
    const float* __restrict__ A2, const float* __restrict__ B2,
    const float* __restrict__ A3, const float* __restrict__ B3,
    const float* __restrict__ DIFFQ, const float* __restrict__ DISC,
    float* __restrict__ out) {
  __shared__ __align__(16) float hs[CD * HP];      // 34816 B  h state
  __shared__ __align__(16) float w4a[64 * 64];     // 16384 B  W4[0:64,:]
  __shared__ __align__(16) float partAB[8 * 64];   //  2048 B  per-wave h_tilde partials
  __shared__ float lg_s[64], tvec_s[64], ht_s[64];
  __shared__ float qe_s[128], qn_s[128];
  __shared__ float ypart[128];
  __shared__ float wab_s[64];

  const int b   = blockIdx.x;
  const int tid = threadIdx.x;
  const int kb  = tid & 15;
  const int cb  = tid >> 4;        // 0..31
  const int wv  = tid >> 6;        // 0..7

  // stage constants + init h
  for (int i = tid; i < 4096; i += 512) w4a[i] = W4[i];
  for (int i = tid; i < 8192; i += 512) { int c = i >> 6, k = i & 63; hs[c * HP + k] = h0[i]; }
  if (tid < 64)  wab_s[tid] = Wab[tid];
  if (tid < 128) qe_s[tid]  = qmat[qs[b * SS] * CD + tid];
  __syncthreads();
  if (tid < 64) {                  // h_tilde0 = q_row0 @ h0
    float a0 = 0.f, a1 = 0.f;
    #pragma unroll 8
    for (int c = 0; c < 128; c += 2) {
      a0 += qe_s[c] * hs[c * HP + tid];
      a1 += qe_s[c + 1] * hs[(c + 1) * HP + tid];
    }
    ht_s[tid] = a0 + a1;
  }
  if (tid == 0) out[b * SS] = 0.f;
  __syncthreads();

  const float bab0 = bab[0];
  const float* W2c = W2 + 128 * 64;   // h_tilde slab
  const float* W3c = W3 + 128 * 64;
  const float* W4b = W4 + 64 * 64;    // LG slab

  for (int t = 1; t < SS; ++t) {
    // --- phase 1 (waves 4..7): load q_matrix rows for t-1 (q_e) and t (q_next)
    if (tid >= 256) {
      int i   = tid & 127;
      int row = (tid < 384) ? qs[b * SS + t - 1] : qs[b * SS + t];
      float v = qmat[row * CD + i];
      if (tid < 384) qe_s[i] = v; else qn_s[i] = v;
    }
    // --- phase A (wave 0): u2,u3 -> LG
    if (tid < 64) {
      int k = tid;
      float base2 = b2[k] + B2[(b * SS + t - 1) * 64 + k];
      float base3 = b3[k] + B3[(b * SS + t - 1) * 64 + k];
      if (t >= 2) {
        base2 += A2[(b * SS + t - 2) * 64 + k];
        base3 += A3[(b * SS + t - 2) * 64 + k];
      }
      float u2a = 0.f, u2b = 0.f, u2c = 0.f, u2d = 0.f;
      float u3a = 0.f, u3b = 0.f, u3c = 0.f, u3d = 0.f;
      #pragma unroll
      for (int j = 0; j < 64; j += 4) {
        float h0v = ht_s[j], h1v = ht_s[j + 1], h2v = ht_s[j + 2], h3v = ht_s[j + 3];
        u2a += h0v * W2c[j * 64 + k];       u2b += h1v * W2c[(j + 1) * 64 + k];
        u2c += h2v * W2c[(j + 2) * 64 + k]; u2d += h3v * W2c[(j + 3) * 64 + k];
        u3a += h0v * W3c[j * 64 + k];       u3b += h1v * W3c[(j + 1) * 64 + k];
        u3c += h2v * W3c[(j + 2) * 64 + k]; u3d += h3v * W3c[(j + 3) * 64 + k];
      }
      float u2 = base2 + (u2a + u2b) + (u2c + u2d);
      float u3 = base3 + (u3a + u3b) + (u3c + u3d);
      float sg = 1.f / (1.f + __expf(-u3));
      float tg = 1.f / (1.f + __expf(-2.f * u2));   // (tanh(u2)+1)/2 == sigmoid(2 u2)
      lg_s[k] = sg * tg;
    }
    __syncthreads();
    // --- phase B (wave 0): tvec = LG@W4b + b4
    if (tid < 64) {
      int k = tid;
      float a0 = 0.f, a1 = 0.f, a2v = 0.f, a3v = 0.f;
      #pragma unroll
      for (int j = 0; j < 64; j += 4) {
        a0  += lg_s[j]     * W4b[j * 64 + k];
        a1  += lg_s[j + 1] * W4b[(j + 1) * 64 + k];
        a2v += lg_s[j + 2] * W4b[(j + 2) * 64 + k];
        a3v += lg_s[j + 3] * W4b[(j + 3) * 64 + k];
      }
      tvec_s[k] = b4[k] + (a0 + a1) + (a2v + a3v);
    }
    __syncthreads();
    // --- phase C (all): gamma_f GEMM + h update + fused reductions
    float acc[4][4];
    #pragma unroll
    for (int i = 0; i < 4; ++i)
      #pragma unroll
      for (int j = 0; j < 4; ++j) acc[i][j] = 0.f;
    #pragma unroll 4
    for (int jq = 0; jq < 16; ++jq) {
      float4 hv[4], wr[4];
      #pragma unroll
      for (int ci = 0; ci < 4; ++ci)
        hv[ci] = *(const float4*)&hs[(cb * 4 + ci) * HP + jq * 4];
      #pragma unroll
      for (int jj = 0; jj < 4; ++jj)
        wr[jj] = *(const float4*)&w4a[(jq * 4 + jj) * 64 + kb * 4];
      #pragma unroll
      for (int ci = 0; ci < 4; ++ci) {
        acc[ci][0] += hv[ci].x * wr[0].x + hv[ci].y * wr[1].x + hv[ci].z * wr[2].x + hv[ci].w * wr[3].x;
        acc[ci][1] += hv[ci].x * wr[0].y + hv[ci].y * wr[1].y + hv[ci].z * wr[2].y + hv[ci].w * wr[3].y;
        acc[ci][2] += hv[ci].x * wr[0].z + hv[ci].y * wr[1].z + hv[ci].z * wr[2].z + hv[ci].w * wr[3].z;
        acc[ci][3] += hv[ci].x * wr[0].w + hv[ci].y * wr[1].w + hv[ci].z * wr[2].w + hv[ci].w * wr[3].w;
      }
    }
    float lgv[4], tvv[4], wbv[4];
    #pragma unroll
    for (int ki = 0; ki < 4; ++ki) {
      lgv[ki] = lg_s[kb * 4 + ki];
      tvv[ki] = tvec_s[kb * 4 + ki];
      wbv[ki] = wab_s[kb * 4 + ki];
    }
    float pk[4] = {0.f, 0.f, 0.f, 0.f};
    float sab[4];
    float4 hnv[4];
    #pragma unroll
    for (int ci = 0; ci < 4; ++ci) {
      int c = cb * 4 + ci;
      float4 hold = *(const float4*)&hs[c * HP + kb * 4];
      float qe = qe_s[c], qn = qn_s[c];
      float4 hn;
      { float g = 1.f / (1.f + __expf(-(acc[ci][0] + tvv[0]))); hn.x = qe * lgv[0] + g * hold.x; }
      { float g = 1.f / (1.f + __expf(-(acc[ci][1] + tvv[1]))); hn.y = qe * lgv[1] + g * hold.y; }
      { float g = 1.f / (1.f + __expf(-(acc[ci][2] + tvv[2]))); hn.z = qe * lgv[2] + g * hold.z; }
      { float g = 1.f / (1.f + __expf(-(acc[ci][3] + tvv[3]))); hn.w = qe * lgv[3] + g * hold.w; }
      hnv[ci] = hn;
      sab[ci] = hn.x * wbv[0] + hn.y * wbv[1] + hn.z * wbv[2] + hn.w * wbv[3];
      pk[0] += qn * hn.x; pk[1] += qn * hn.y; pk[2] += qn * hn.z; pk[3] += qn * hn.w;
    }
    #pragma unroll
    for (int ci = 0; ci < 4; ++ci)
      *(float4*)&hs[(cb * 4 + ci) * HP + kb * 4] = hnv[ci];   // rows are wave-private
    // h_tilde partials: reduce over c-groups within wave (lane bits 4,5)
    #pragma unroll
    for (int ki = 0; ki < 4; ++ki) {
      pk[ki] += __shfl_xor(pk[ki], 16);
      pk[ki] += __shfl_xor(pk[ki], 32);
    }
    if ((tid & 48) == 0)
      *(float4*)&partAB[wv * 64 + kb * 4] = make_float4(pk[0], pk[1], pk[2], pk[3]);
    // ability: reduce over k (lane bits 0..3), then finish ypart
    #pragma unroll
    for (int ci = 0; ci < 4; ++ci) {
      sab[ci] += __shfl_xor(sab[ci], 1);
      sab[ci] += __shfl_xor(sab[ci], 2);
      sab[ci] += __shfl_xor(sab[ci], 4);
      sab[ci] += __shfl_xor(sab[ci], 8);
    }
    if ((tid & 15) == 0) {
      #pragma unroll
      for (int ci = 0; ci < 4; ++ci) {
        int c = cb * 4 + ci;
        float ab = qn_s[c] / (1.f + __expf(-(sab[ci] + bab0)));
        ypart[c] = ab - DIFFQ[(b * SS + t) * CD + c];
      }
    }
    __syncthreads();
    // --- phase D: wave0 finishes h_tilde; wave1 reduces y and writes pred
    if (tid < 64) {
      float s = 0.f;
      #pragma unroll
      for (int w = 0; w < 8; ++w) s += partAB[w * 64 + tid];
      ht_s[tid] = s;
    } else if (tid < 128) {
      int l = tid - 64;
      float v = ypart[l] + ypart[l + 64];
      v += __shfl_xor(v, 32); v += __shfl_xor(v, 16); v += __shfl_xor(v, 8);
      v += __shfl_xor(v, 4);  v += __shfl_xor(v, 2);  v += __shfl_xor(v, 1);
      if (l == 0) out[b * SS + t] = 1.f / (1.f + __expf(-DISC[b * SS + t] * v));
    }
    __syncthreads();
  }
}

// ---------------------------------------------------------------------------
extern "C" void kernel_launch(void* const* d_in, const int* in_sizes, int n_in,
                              void* d_out, int out_size, void* d_ws, size_t ws_size,
                              hipStream_t stream) {
  const int*   qs    = (const int*)d_in[0];
  const int*   cs    = (const int*)d_in[1];
  const float* qmat  = (const float*)d_in[2];
  const float* Eq    = (const float*)d_in[3];
  const float* Ec    = (const float*)d_in[4];
  const float* h0    = (const float*)d_in[5];
  const float* W1    = (const float*)d_in[6];
  const float* b1    = (const float*)d_in[7];
  const float* W2    = (const float*)d_in[8];
  const float* b2    = (const float*)d_in[9];
  const float* W3    = (const float*)d_in[10];
  const float* b3    = (const float*)d_in[11];
  const float* W4    = (const float*)d_in[12];
  const float* b4    = (const float*)d_in[13];
  const float* Wab   = (const float*)d_in[14];
  const float* bab   = (const float*)d_in[15];
  const float* Wdiff = (const float*)d_in[16];
  const float* bdiff = (const float*)d_in[17];
  const float* Wdisc = (const float*)d_in[18];
  const float* bdisc = (const float*)d_in[19];
  float* out = (float*)d_out;

  float* w = (float*)d_ws;
  const size_t NBS = (size_t)BB * SS * KK;   // 524288
  float* A2    = w;
  float* B2    = A2 + NBS;
  float* A3    = B2 + NBS;
  float* B3    = A3 + NBS;
  float* DIFFQ = B3 + NBS;                   // BB*SS*CD = 1048576
  float* DISC  = DIFFQ + (size_t)BB * SS * CD;

  precompute1<<<BB * SS, 64, 0, stream>>>(qs, cs, Eq, Ec, W1, b1, W2, W3, A2, B2, A3, B3);
  precompute2<<<BB * SS, 128, 0, stream>>>(qs, Eq, qmat, Wdiff, bdiff, Wdisc, bdisc, DIFFQ, DISC);
  lpkt_main<<<BB, 512, 0, stream>>>(qs, qmat, h0, W2, b2, W3, b3, W4, b4, Wab, bab,
                                    A2, B2, A3, B3, DIFFQ, DISC, out);
}

// Round 2
// 518.375 us; speedup vs baseline: 6.1885x; 6.1885x over previous
//
#include <hip/hip_runtime.h>

// LPKT forward. B=64, S=128, NQ=2000, C=128, K=64, DE=DC=64.
// R2: MFMA-based recurrence. 1 WG/batch, 8 waves, h fp32-resident in LDS,
// all weight matrices as persistent in-register bf16 MFMA B-fragments,
// 2 barriers/step, one-step-ahead prefetch of all per-step global reads.

constexpr int BB = 64;    // batch
constexpr int SS = 128;   // seq len
constexpr int CD = 128;   // C (concepts)
constexpr int KK = 64;    // K
constexpr int HP = 68;    // padded LDS row stride for h (float units; 272B, 16B-aligned)

typedef short bf16x8 __attribute__((ext_vector_type(8)));
typedef float f32x4  __attribute__((ext_vector_type(4)));

__device__ __forceinline__ short f2bf(float x) {           // fp32 -> bf16 RNE
  unsigned u = __builtin_bit_cast(unsigned, x);
  unsigned r = u + 0x7fffu + ((u >> 16) & 1u);
  return (short)(r >> 16);
}
__device__ __forceinline__ float sigm(float x) { return 1.f / (1.f + __expf(-x)); }
__device__ __forceinline__ bf16x8 pack8(float4 a, float4 b) {
  bf16x8 r;
  r[0] = f2bf(a.x); r[1] = f2bf(a.y); r[2] = f2bf(a.z); r[3] = f2bf(a.w);
  r[4] = f2bf(b.x); r[5] = f2bf(b.y); r[6] = f2bf(b.z); r[7] = f2bf(b.w);
  return r;
}

// ---------------------------------------------------------------------------
// P1: all_learning = [e_emb|c_emb]@W1+b1 projected through W2/W3 k-slabs.
__global__ void precompute1(const int* __restrict__ qs, const int* __restrict__ cs,
                            const float* __restrict__ Eq, const float* __restrict__ Ec,
                            const float* __restrict__ W1, const float* __restrict__ b1,
                            const float* __restrict__ W2, const float* __restrict__ W3,
                            float* __restrict__ A2, float* __restrict__ B2,
                            float* __restrict__ A3, float* __restrict__ B3) {
  int bs = blockIdx.x;
  int k  = threadIdx.x;            // 0..63
  int q  = qs[bs], cr = cs[bs];
  __shared__ float eq[64], ec[64], al[64];
  eq[k] = Eq[q * 64 + k];
  ec[k] = Ec[cr * 64 + k];
  __syncthreads();
  float a0 = 0.f, a1 = 0.f, a2i = 0.f, a3i = 0.f;
  #pragma unroll
  for (int d = 0; d < 64; d += 4) {
    a0  += eq[d]   * W1[d * 64 + k];
    a1  += eq[d+1] * W1[(d+1) * 64 + k];
    a2i += eq[d+2] * W1[(d+2) * 64 + k];
    a3i += eq[d+3] * W1[(d+3) * 64 + k];
  }
  #pragma unroll
  for (int d = 0; d < 64; d += 4) {
    a0  += ec[d]   * W1[(64+d) * 64 + k];
    a1  += ec[d+1] * W1[(64+d+1) * 64 + k];
    a2i += ec[d+2] * W1[(64+d+2) * 64 + k];
    a3i += ec[d+3] * W1[(64+d+3) * 64 + k];
  }
  al[k] = ((a0 + a1) + (a2i + a3i)) + b1[k];
  __syncthreads();
  float r2a = 0.f, r2b = 0.f, r3a = 0.f, r3b = 0.f;
  float s2a = 0.f, s2b = 0.f, s3a = 0.f, s3b = 0.f;
  #pragma unroll
  for (int j = 0; j < 64; j += 2) {
    float v0 = al[j], v1 = al[j+1];
    r2a += v0 * W2[j * 64 + k];        s2a += v1 * W2[(j+1) * 64 + k];
    r2b += v0 * W2[(64+j) * 64 + k];   s2b += v1 * W2[(64+j+1) * 64 + k];
    r3a += v0 * W3[j * 64 + k];        s3a += v1 * W3[(j+1) * 64 + k];
    r3b += v0 * W3[(64+j) * 64 + k];   s3b += v1 * W3[(64+j+1) * 64 + k];
  }
  A2[bs * 64 + k] = r2a + s2a;
  B2[bs * 64 + k] = r2b + s2b;
  A3[bs * 64 + k] = r3a + s3a;
  B3[bs * 64 + k] = r3b + s3b;
}

// ---------------------------------------------------------------------------
// P2: DIFFQ[b,s,c] = sigmoid(E_q@Wdiff+bdiff)*q_matrix[q]; DISC = 5*sigmoid(..).
__global__ void precompute2(const int* __restrict__ qs, const float* __restrict__ Eq,
                            const float* __restrict__ qmat,
                            const float* __restrict__ Wdiff, const float* __restrict__ bdiff,
                            const float* __restrict__ Wdisc, const float* __restrict__ bdisc,
                            float* __restrict__ DIFFQ, float* __restrict__ DISC) {
  int bs = blockIdx.x;
  int c  = threadIdx.x;            // 0..127
  int q  = qs[bs];
  __shared__ float e[64];
  if (c < 64) e[c] = Eq[q * 64 + c];
  __syncthreads();
  float a0 = 0.f, a1 = 0.f, a2 = 0.f, a3 = 0.f;
  #pragma unroll
  for (int d = 0; d < 64; d += 4) {
    a0 += e[d]   * Wdiff[d * 128 + c];
    a1 += e[d+1] * Wdiff[(d+1) * 128 + c];
    a2 += e[d+2] * Wdiff[(d+2) * 128 + c];
    a3 += e[d+3] * Wdiff[(d+3) * 128 + c];
  }
  float acc = ((a0 + a1) + (a2 + a3)) + bdiff[c];
  float qv  = qmat[q * 128 + c];
  DIFFQ[bs * 128 + c] = qv / (1.f + __expf(-acc));
  if (c == 0) {
    float d0 = 0.f, d1 = 0.f;
    #pragma unroll
    for (int d = 0; d < 64; d += 2) { d0 += e[d] * Wdisc[d]; d1 += e[d+1] * Wdisc[d+1]; }
    DISC[bs] = 5.f / (1.f + __expf(-(d0 + d1 + bdisc[0])));
  }
}

// ---------------------------------------------------------------------------
// Main sequential kernel. grid=64 (1 WG/batch), block=512 (8 waves).
// Wave w owns h rows [16w, 16w+16): read (MFMA A-frags, hold) and write (update)
// are strictly wave-private -> no barrier around the state update.
// MFMA 16x16x32 bf16 layouts (HW-verified A/C/D, B by standard CDNA pattern):
//   A[m][k]: m=lane&15, k=(lane>>4)*8+j    B[k][n]: n=lane&15, k=(lane>>4)*8+j
//   D[row][col]: col=lane&15, row=(lane>>4)*4+reg
__global__ __launch_bounds__(512, 2) void lpkt_main(
    const int* __restrict__ qs, const float* __restrict__ qmat,
    const float* __restrict__ h0,
    const float* __restrict__ W2, const float* __restrict__ b2,
    const float* __restrict__ W3, const float* __restrict__ b3,
    const float* __restrict__ W4, const float* __restrict__ b4,
    const float* __restrict__ Wab, const float* __restrict__ bab,
    const float* __restrict__ A2, const float* __restrict__ B2,
    const float* __restrict__ A3, const float* __restrict__ B3,
    const float* __restrict__ DIFFQ, const float* __restrict__ DISC,
    float* __restrict__ out) {
  __shared__ __align__(16) float hs[CD * HP];     // 34816 B fp32 h state
  __shared__ __align__(16) float qrow[2][CD];     // ping-pong q_matrix rows
  __shared__ __align__(16) float lg_s[KK], tvec_s[KK], ht_s[KK], wab_s[KK];
  __shared__ __align__(16) float partAB[8 * KK];  // per-wave h_tilde partials
  __shared__ __align__(16) float ypart[CD];       // raw ability sums (pre-sigmoid)

  const int b    = blockIdx.x;
  const int tid  = threadIdx.x;
  const int lane = tid & 63;
  const int wv   = tid >> 6;       // 0..7
  const int col  = lane & 15;
  const int q    = lane >> 4;      // 0..3
  const int bS   = b * SS;

  // ---- init staging ----
  for (int i = tid; i < 8192; i += 512) hs[(i >> 6) * HP + (i & 63)] = h0[i];
  if (tid < 128) qrow[0][tid] = qmat[qs[bS] * CD + tid];
  if (tid < 64)  wab_s[tid] = Wab[tid];
  if (tid == 0)  out[bS] = 0.f;

  const float* W4a = W4;                 // h slab of W4
  const float* W4b = W4 + 64 * 64;       // LG slab of W4
  const float* W2c = W2 + 128 * 64;      // h_tilde slab of W2
  const float* W3c = W3 + 128 * 64;
  const float bab0 = bab[0];

  // persistent B-fragments (bf16): W4a for all waves; W2c/W3c/W4b on wave0
  bf16x8 bw4[4][2];
  #pragma unroll
  for (int n = 0; n < 4; ++n)
    #pragma unroll
    for (int kh = 0; kh < 2; ++kh)
      #pragma unroll
      for (int j = 0; j < 8; ++j)
        bw4[n][kh][j] = f2bf(W4a[(kh * 32 + q * 8 + j) * 64 + n * 16 + col]);

  bf16x8 bw2[4][2], bw3[4][2], bwb[4][2];
  float b2r[4], b3r[4], b4r[4];
  float cB2[4], cA2[4], cB3[4], cA3[4];
  if (wv == 0) {
    #pragma unroll
    for (int n = 0; n < 4; ++n) {
      #pragma unroll
      for (int kh = 0; kh < 2; ++kh)
        #pragma unroll
        for (int j = 0; j < 8; ++j) {
          int kk = (kh * 32 + q * 8 + j) * 64 + n * 16 + col;
          bw2[n][kh][j] = f2bf(W2c[kk]);
          bw3[n][kh][j] = f2bf(W3c[kk]);
          bwb[n][kh][j] = f2bf(W4b[kk]);
        }
      int k = n * 16 + col;
      b2r[n] = b2[k]; b3r[n] = b3[k]; b4r[n] = b4[k];
      cB2[n] = B2[(bS + 0) * 64 + k]; cB3[n] = B3[(bS + 0) * 64 + k];
      cA2[n] = 0.f; cA3[n] = 0.f;
    }
  }
  __syncthreads();

  // h_tilde0 = qrow0 @ h0 (wave0, kept in register)
  float htv = 0.f;
  if (wv == 0) {
    float s0 = 0.f, s1 = 0.f;
    #pragma unroll 8
    for (int c = 0; c < 128; c += 2) {
      s0 += qrow[0][c] * hs[c * HP + lane];
      s1 += qrow[0][c + 1] * hs[(c + 1) * HP + lane];
    }
    htv = s0 + s1;
  }

  float dq0 = 0.f, dq1 = 0.f, dsc = 0.f;
  const f32x4 zz = {0.f, 0.f, 0.f, 0.f};

  for (int t = 1; t < SS; ++t) {
    // ================= HEAD (pre-B1) =================
    if (wv == 0) {
      if (t > 1) {                      // reduce h_tilde partials from step t-1
        float s = 0.f;
        #pragma unroll
        for (int w = 0; w < 8; ++w) s += partAB[w * 64 + lane];
        htv = s;
      }
      ht_s[lane] = htv;
      float base2[4], base3[4];
      #pragma unroll
      for (int n = 0; n < 4; ++n) {
        base2[n] = b2r[n] + cB2[n] + cA2[n];
        base3[n] = b3r[n] + cB3[n] + cA3[n];
      }
      if (t < SS - 1) {                 // prefetch consts for step t+1
        #pragma unroll
        for (int n = 0; n < 4; ++n) {
          int k = n * 16 + col;
          cB2[n] = B2[(bS + t) * 64 + k];
          cA2[n] = A2[(bS + t - 1) * 64 + k];
          cB3[n] = B3[(bS + t) * 64 + k];
          cA3[n] = A3[(bS + t - 1) * 64 + k];
        }
      }
      // u2/u3 GEMVs via MFMA (ht row-replicated across m)
      float4 x0 = *(const float4*)&ht_s[q * 8];
      float4 x1 = *(const float4*)&ht_s[q * 8 + 4];
      float4 x2 = *(const float4*)&ht_s[32 + q * 8];
      float4 x3 = *(const float4*)&ht_s[32 + q * 8 + 4];
      bf16x8 hf0 = pack8(x0, x1), hf1 = pack8(x2, x3);
      f32x4 a2v[4], a3v[4];
      #pragma unroll
      for (int n = 0; n < 4; ++n) {
        a2v[n] = __builtin_amdgcn_mfma_f32_16x16x32_bf16(hf0, bw2[n][0], zz, 0, 0, 0);
        a2v[n] = __builtin_amdgcn_mfma_f32_16x16x32_bf16(hf1, bw2[n][1], a2v[n], 0, 0, 0);
        a3v[n] = __builtin_amdgcn_mfma_f32_16x16x32_bf16(hf0, bw3[n][0], zz, 0, 0, 0);
        a3v[n] = __builtin_amdgcn_mfma_f32_16x16x32_bf16(hf1, bw3[n][1], a3v[n], 0, 0, 0);
      }
      float lgn[4];
      #pragma unroll
      for (int n = 0; n < 4; ++n) {
        float u2 = a2v[n][0] + base2[n];
        float u3 = a3v[n][0] + base3[n];
        lgn[n] = sigm(u3) * sigm(2.f * u2);   // sigmoid(g3)*(tanh(g2)+1)/2
      }
      if (q == 0) {
        #pragma unroll
        for (int n = 0; n < 4; ++n) lg_s[n * 16 + col] = lgn[n];
      }
      // tvec = LG @ W4b + b4 (same-wave LDS round trip for the broadcast)
      float4 l0 = *(const float4*)&lg_s[q * 8];
      float4 l1 = *(const float4*)&lg_s[q * 8 + 4];
      float4 l2 = *(const float4*)&lg_s[32 + q * 8];
      float4 l3 = *(const float4*)&lg_s[32 + q * 8 + 4];
      bf16x8 lf0 = pack8(l0, l1), lf1 = pack8(l2, l3);
      #pragma unroll
      for (int n = 0; n < 4; ++n) {
        f32x4 bb = __builtin_amdgcn_mfma_f32_16x16x32_bf16(lf0, bwb[n][0], zz, 0, 0, 0);
        bb = __builtin_amdgcn_mfma_f32_16x16x32_bf16(lf1, bwb[n][1], bb, 0, 0, 0);
        if (q == 0) tvec_s[n * 16 + col] = bb[0] + b4r[n];
      }
    } else if (wv == 1) {               // prefetch DIFFQ/DISC for this step's tail
      dq0 = DIFFQ[(bS + t) * CD + lane];
      dq1 = DIFFQ[(bS + t) * CD + 64 + lane];
      dsc = DISC[bS + t];
    } else if (wv == 2) {               // load q_next row into ping-pong slot
      int row = qs[bS + t];
      qrow[t & 1][lane]      = qmat[row * CD + lane];
      qrow[t & 1][64 + lane] = qmat[row * CD + 64 + lane];
    }
    // G = h @ W4a for this wave's 16-row band (all waves, wave-private h rows)
    const int r = 16 * wv + col;
    float4 g0 = *(const float4*)&hs[r * HP + q * 8];
    float4 g1 = *(const float4*)&hs[r * HP + q * 8 + 4];
    float4 g2 = *(const float4*)&hs[r * HP + 32 + q * 8];
    float4 g3 = *(const float4*)&hs[r * HP + 32 + q * 8 + 4];
    bf16x8 af0 = pack8(g0, g1), af1 = pack8(g2, g3);
    f32x4 acc[4];
    #pragma unroll
    for (int n = 0; n < 4; ++n) {
      acc[n] = __builtin_amdgcn_mfma_f32_16x16x32_bf16(af0, bw4[n][0], zz, 0, 0, 0);
      acc[n] = __builtin_amdgcn_mfma_f32_16x16x32_bf16(af1, bw4[n][1], acc[n], 0, 0, 0);
    }
    __syncthreads();                    // B1: lg/tvec/qrow published

    // ================= UPDATE =================
    const float* qe = qrow[(t - 1) & 1];
    const float* qn = qrow[t & 1];
    float lgv[4], tvv[4], wbv[4];
    #pragma unroll
    for (int n = 0; n < 4; ++n) {
      int k = n * 16 + col;
      lgv[n] = lg_s[k]; tvv[n] = tvec_s[k]; wbv[n] = wab_s[k];
    }
    float qev[4], qnv[4];
    #pragma unroll
    for (int reg = 0; reg < 4; ++reg) {
      int c = 16 * wv + 4 * q + reg;
      qev[reg] = qe[c]; qnv[reg] = qn[c];
    }
    float sab[4] = {0.f, 0.f, 0.f, 0.f};
    float pk[4]  = {0.f, 0.f, 0.f, 0.f};
    #pragma unroll
    for (int reg = 0; reg < 4; ++reg) {
      int c = 16 * wv + 4 * q + reg;
      #pragma unroll
      for (int n = 0; n < 4; ++n) {
        int idx = c * HP + n * 16 + col;
        float hold = hs[idx];
        float g = sigm(acc[n][reg] + tvv[n]);
        float h2 = qev[reg] * lgv[n] + g * hold;
        hs[idx] = h2;
        sab[reg] += h2 * wbv[n];
        pk[n]    += qnv[reg] * h2;
      }
    }
    #pragma unroll
    for (int reg = 0; reg < 4; ++reg) {  // reduce ability over k (col bits)
      sab[reg] += __shfl_xor(sab[reg], 1);
      sab[reg] += __shfl_xor(sab[reg], 2);
      sab[reg] += __shfl_xor(sab[reg], 4);
      sab[reg] += __shfl_xor(sab[reg], 8);
    }
    if (col == 0) {
      #pragma unroll
      for (int reg = 0; reg < 4; ++reg) ypart[16 * wv + 4 * q + reg] = sab[reg];
    }
    #pragma unroll
    for (int n = 0; n < 4; ++n) {        // reduce h_tilde partial over c (q bits)
      pk[n] += __shfl_xor(pk[n], 16);
      pk[n] += __shfl_xor(pk[n], 32);
    }
    if (q == 0) {
      #pragma unroll
      for (int n = 0; n < 4; ++n) partAB[wv * 64 + n * 16 + col] = pk[n];
    }
    __syncthreads();                    // B2: partials/ypart published

    // ================= TAIL =================
    if (wv == 1) {
      float v = (sigm(ypart[lane] + bab0) * qn[lane] - dq0)
              + (sigm(ypart[64 + lane] + bab0) * qn[64 + lane] - dq1);
      v += __shfl_xor(v, 32); v += __shfl_xor(v, 16); v += __shfl_xor(v, 8);
      v += __shfl_xor(v, 4);  v += __shfl_xor(v, 2);  v += __shfl_xor(v, 1);
      if (lane == 0) out[bS + t] = sigm(dsc * v);
    }
  }
}

// ---------------------------------------------------------------------------
extern "C" void kernel_launch(void* const* d_in, const int* in_sizes, int n_in,
                              void* d_out, int out_size, void* d_ws, size_t ws_size,
                              hipStream_t stream) {
  const int*   qs    = (const int*)d_in[0];
  const int*   cs    = (const int*)d_in[1];
  const float* qmat  = (const float*)d_in[2];
  const float* Eq    = (const float*)d_in[3];
  const float* Ec    = (const float*)d_in[4];
  const float* h0    = (const float*)d_in[5];
  const float* W1    = (const float*)d_in[6];
  const float* b1    = (const float*)d_in[7];
  const float* W2    = (const float*)d_in[8];
  const float* b2    = (const float*)d_in[9];
  const float* W3    = (const float*)d_in[10];
  const float* b3    = (const float*)d_in[11];
  const float* W4    = (const float*)d_in[12];
  const float* b4    = (const float*)d_in[13];
  const float* Wab   = (const float*)d_in[14];
  const float* bab   = (const float*)d_in[15];
  const float* Wdiff = (const float*)d_in[16];
  const float* bdiff = (const float*)d_in[17];
  const float* Wdisc = (const float*)d_in[18];
  const float* bdisc = (const float*)d_in[19];
  float* out = (float*)d_out;

  float* w = (float*)d_ws;
  const size_t NBS = (size_t)BB * SS * KK;   // 524288
  float* A2    = w;
  float* B2    = A2 + NBS;
  float* A3    = B2 + NBS;
  float* B3    = A3 + NBS;
  float* DIFFQ = B3 + NBS;                   // BB*SS*CD = 1048576
  float* DISC  = DIFFQ + (size_t)BB * SS * CD;

  precompute1<<<BB * SS, 64, 0, stream>>>(qs, cs, Eq, Ec, W1, b1, W2, W3, A2, B2, A3, B3);
  precompute2<<<BB * SS, 128, 0, stream>>>(qs, Eq, qmat, Wdiff, bdiff, Wdisc, bdisc, DIFFQ, DISC);
  lpkt_main<<<BB, 512, 0, stream>>>(qs, qmat, h0, W2, b2, W3, b3, W4, b4, Wab, bab,
                                    A2, B2, A3, B3, DIFFQ, DISC, out);
}